// Round 2
// baseline (918.603 us; speedup 1.0000x reference)
//
#include <hip/hip_runtime.h>

#define N_NODES 100000
#define NPAD    100096   // 782 * 128; row NPAD is the all-zero dummy row
#define E_EDGES 800000

typedef _Float16 f16;
typedef _Float16 f16x4 __attribute__((ext_vector_type(4)));
typedef _Float16 f16x8 __attribute__((ext_vector_type(8)));
typedef float    f32x4 __attribute__((ext_vector_type(4)));

__device__ inline void async16(const void* g, void* l) {
    __builtin_amdgcn_global_load_lds(
        (const __attribute__((address_space(1))) void*)g,
        (__attribute__((address_space(3))) void*)l, 16, 0, 0);
}

// ---------------- graph build ----------------
__global__ void k_deg(const int* __restrict__ ei, int* __restrict__ deg) {
    int e = blockIdx.x * 256 + threadIdx.x;
    if (e < E_EDGES) atomicAdd(&deg[ei[e]], 1);
}

// scan over PADDED degrees (round up to multiple of 4) so every CSR row is
// a whole number of int4 groups; also emit dinv (zeroed for pad rows).
__global__ void k_scan1(const int* __restrict__ deg, int* __restrict__ off,
                        int* __restrict__ bsum, float* __restrict__ dinv) {
    __shared__ int s[256];
    int i = blockIdx.x * 256 + threadIdx.x;
    int d = (i < N_NODES) ? deg[i] : 0;
    int pd = (d + 3) & ~3;
    // grid covers exactly NPAD indices (391*256); zero dinv for pad rows
    dinv[i] = (i < N_NODES) ? rsqrtf((float)(d + 1)) : 0.f;  // +1 self loop
    s[threadIdx.x] = pd;
    __syncthreads();
    for (int dd = 1; dd < 256; dd <<= 1) {
        int t = (threadIdx.x >= dd) ? s[threadIdx.x - dd] : 0;
        __syncthreads();
        s[threadIdx.x] += t;
        __syncthreads();
    }
    if (i < N_NODES) off[i] = s[threadIdx.x] - pd;   // exclusive
    if (threadIdx.x == 255) bsum[blockIdx.x] = s[255];
}

__global__ void k_scan2(int* __restrict__ bsum, int nb) {
    __shared__ int s[512];
    int tid = threadIdx.x;
    int v = (tid < nb) ? bsum[tid] : 0;
    s[tid] = v;
    __syncthreads();
    for (int d = 1; d < 512; d <<= 1) {
        int t = (tid >= d) ? s[tid - d] : 0;
        __syncthreads();
        s[tid] += t;
        __syncthreads();
    }
    if (tid < nb) bsum[tid] = s[tid] - v;
}

// finalize offsets AND write the (<=3 per node) dummy padding entries
__global__ void k_scan3(int* __restrict__ off, const int* __restrict__ bsum,
                        const int* __restrict__ deg, int* __restrict__ csr) {
    int i = blockIdx.x * 256 + threadIdx.x;
    if (i >= N_NODES) return;
    int o = off[i] + bsum[blockIdx.x];
    off[i] = o;
    int d = deg[i], pd = (d + 3) & ~3;
    for (int k = d; k < pd; ++k) csr[o + k] = NPAD;   // dummy zero row
    if (i == N_NODES - 1) off[N_NODES] = o + pd;
}

__global__ void k_fill(const int* __restrict__ ei, const int* __restrict__ off,
                       int* __restrict__ cursor, int* __restrict__ csr) {
    int e = blockIdx.x * 256 + threadIdx.x;
    if (e >= E_EDGES) return;
    int dst = ei[e];
    int src = ei[E_EDGES + e];
    int pos = atomicAdd(&cursor[dst], 1);
    csr[off[dst] + pos] = src;
}

// ---------------- conversions ----------------
// x -> f16, pre-scaled by dinv[node] (single f16 rounding of the product)
__global__ void k_x_to_f16(const float* __restrict__ x,
                           const float* __restrict__ dinv,
                           f16* __restrict__ xh) {
    int i = blockIdx.x * 256 + threadIdx.x;
    if (i >= N_NODES * 64) return;          // 64 float4 per node (256 ch)
    float d = dinv[i >> 6];
    float4 v = ((const float4*)x)[i];
    f16x4 o;
    o.x = (f16)(v.x * d); o.y = (f16)(v.y * d);
    o.z = (f16)(v.z * d); o.w = (f16)(v.w * d);
    ((f16x4*)xh)[i] = o;
}

__global__ void k_transpose(const float* __restrict__ W, f16* __restrict__ Wt,
                            int K, int M) {
    int m = blockIdx.x * 256 + threadIdx.x;
    int k = blockIdx.y;
    if (m < M) Wt[(size_t)m * K + k] = (f16)W[(size_t)k * M + m];
}

// ---------------- GEMM: C[NPAD x M] = A[NPAD x K] * Bt[M x K]^T ----------------
// 128x128 tile, 4 waves (2x2), wave-tile 64x64, BK=32 (m97 structure).
// MODE: 0 = raw f16 out, 1 = bias+relu f16 out, 2 = bias f32 out (guarded),
//       3 = row-scale by dsc[row] (dinv pre-scaling), f16 out
template<int K, int M, int MODE>
__launch_bounds__(256, 2)
__global__ void k_gemm(const f16* __restrict__ A, const f16* __restrict__ B,
                       void* __restrict__ C, const float* __restrict__ bias,
                       const float* __restrict__ dsc) {
    __shared__ __align__(16) char smem[16384];
    f16* As = (f16*)smem;             // 128*32 = 8 KB
    f16* Bs = (f16*)(smem + 8192);    // 128*32 = 8 KB
    int tid  = threadIdx.x;
    int wave = tid >> 6, lane = tid & 63;
    int wr = (wave >> 1) * 64, wc = (wave & 1) * 64;
    int lm = lane & 15, q = lane >> 4;
    int rowBase = blockIdx.x * 128;
    int colBase = blockIdx.y * 128;

    f32x4 acc[4][4] = {};
    const f16* Ag = A + (size_t)rowBase * K;
    const f16* Bg = B + (size_t)colBase * K;

    int c0 = tid, c1 = tid + 256;   // 16B chunk ids: row = c>>2, seg = c&3
    for (int kt = 0; kt < K; kt += 32) {
        __syncthreads();
        async16(Ag + (size_t)(c0 >> 2) * K + kt + (c0 & 3) * 8, &As[c0 * 8]);
        async16(Ag + (size_t)(c1 >> 2) * K + kt + (c1 & 3) * 8, &As[c1 * 8]);
        async16(Bg + (size_t)(c0 >> 2) * K + kt + (c0 & 3) * 8, &Bs[c0 * 8]);
        async16(Bg + (size_t)(c1 >> 2) * K + kt + (c1 & 3) * 8, &Bs[c1 * 8]);
        __syncthreads();

        f16x8 a[4], b[4];
#pragma unroll
        for (int i = 0; i < 4; ++i) {
            a[i] = *(const f16x8*)&As[(wr + i * 16 + lm) * 32 + q * 8];
            b[i] = *(const f16x8*)&Bs[(wc + i * 16 + lm) * 32 + q * 8];
        }
#pragma unroll
        for (int i = 0; i < 4; ++i)
#pragma unroll
            for (int j = 0; j < 4; ++j)
                acc[i][j] = __builtin_amdgcn_mfma_f32_16x16x32_f16(
                    a[i], b[j], acc[i][j], 0, 0, 0);
    }

    if (MODE == 2) {
        // fp32 output (final FC) — guarded scalar stores
#pragma unroll
        for (int i = 0; i < 4; ++i) {
            int gr0 = rowBase + wr + i * 16 + q * 4;
#pragma unroll
            for (int j = 0; j < 4; ++j) {
                int gc = colBase + wc + j * 16 + lm;
                float bj = bias[gc];
#pragma unroll
                for (int r = 0; r < 4; ++r) {
                    int gr = gr0 + r;
                    if (gr < N_NODES)
                        ((float*)C)[(size_t)gr * M + gc] = acc[i][j][r] + bj;
                }
            }
        }
    } else {
        // f16 output: LDS transpose -> f16x8 (dwordx4) stores, no guards
        __syncthreads();
        f16* Ep = (f16*)smem + wave * (16 * 80);   // 2560 B/wave, stride 80 f16
#pragma unroll
        for (int i = 0; i < 4; ++i) {
            f32x4 dr = {1.f, 1.f, 1.f, 1.f};
            if (MODE == 3)
                dr = *(const f32x4*)&dsc[rowBase + wr + i * 16 + q * 4];
#pragma unroll
            for (int j = 0; j < 4; ++j) {
                int colg = colBase + wc + j * 16 + lm;
#pragma unroll
                for (int r = 0; r < 4; ++r) {
                    float v = acc[i][j][r];
                    if (MODE == 1) {
                        v += bias[colg];
                        v = v > 0.f ? v : 0.f;
                    }
                    if (MODE == 3) v *= dr[r];
                    Ep[(q * 4 + r) * 80 + j * 16 + lm] = (f16)v;
                }
            }
            __syncthreads();
            int row0 = lane >> 3, c8 = lane & 7;
            f16x8 v0 = *(const f16x8*)&Ep[row0 * 80 + c8 * 8];
            f16x8 v1 = *(const f16x8*)&Ep[(row0 + 8) * 80 + c8 * 8];
            int gr0 = rowBase + wr + i * 16 + row0;
            int gc  = colBase + wc + c8 * 8;
            *(f16x8*)&((f16*)C)[(size_t)gr0 * M + gc] = v0;
            *(f16x8*)&((f16*)C)[(size_t)(gr0 + 8) * M + gc] = v1;
            __syncthreads();
        }
    }
}

// ---------------- aggregation (contiguous, CH channels, prescaled rows) ----------------
// rows of t are already scaled by dinv[src]; CSR rows are padded to x4 with
// the dummy zero row (index NPAD). One wave per node.
// CH=512: f16x8 (16B/lane); CH=256: f16x4 (8B/lane).
template<int VE> struct VecT;
template<> struct VecT<4> { typedef f16x4 type; };
template<> struct VecT<8> { typedef f16x8 type; };

template<int CH, bool ACT>
__launch_bounds__(256)
__global__ void k_agg(const f16* __restrict__ t, const int* __restrict__ off,
                      const int* __restrict__ csr, const float* __restrict__ dinv,
                      const float* __restrict__ bias, f16* __restrict__ h) {
    constexpr int VE = CH / 64;
    typedef typename VecT<VE>::type vec;
    int node = blockIdx.x * 4 + (threadIdx.x >> 6);
    if (node >= N_NODES) return;
    int lane = threadIdx.x & 63;
    const vec* __restrict__ rows = (const vec*)t;

    vec v = rows[node * 64 + lane];          // self (already dinv-scaled)
    float acc[VE];
#pragma unroll
    for (int j = 0; j < VE; ++j) acc[j] = (float)v[j];

    int s = off[node], e = off[node + 1];    // multiple-of-4 row, 16B aligned
    if (s < e) {
        int4 iv = *(const int4*)&csr[s];
        for (int idx = s; idx < e; idx += 4) {
            // prefetch next group; may over-read into pad — values are only
            // used as addresses if the loop re-enters (idx+4 < e), so safe.
            int4 nxt = *(const int4*)&csr[idx + 4];
            vec u0 = rows[iv.x * 64 + lane];
            vec u1 = rows[iv.y * 64 + lane];
            vec u2 = rows[iv.z * 64 + lane];
            vec u3 = rows[iv.w * 64 + lane];
            iv = nxt;
#pragma unroll
            for (int j = 0; j < VE; ++j)
                acc[j] += ((float)u0[j] + (float)u1[j])
                        + ((float)u2[j] + (float)u3[j]);
        }
    }

    float di = dinv[node];
    vec o;
#pragma unroll
    for (int j = 0; j < VE; ++j) {
        float r = di * acc[j];
        if (ACT) {
            r += bias[lane * VE + j];
            r = r > 0.f ? r : 0.f;
        }
        o[j] = (f16)r;
    }
    ((vec*)h)[node * 64 + lane] = o;
}

// ---------------- launch ----------------
extern "C" void kernel_launch(void* const* d_in, const int* in_sizes, int n_in,
                              void* d_out, int out_size, void* d_ws, size_t ws_size,
                              hipStream_t stream) {
    const float* x   = (const float*)d_in[0];
    const int*   ei  = (const int*)d_in[1];
    const float* W1  = (const float*)d_in[2];
    const float* b1  = (const float*)d_in[3];
    const float* W2  = (const float*)d_in[4];
    const float* b2  = (const float*)d_in[5];
    const float* W3  = (const float*)d_in[6];
    const float* b3  = (const float*)d_in[7];
    const float* Wfc = (const float*)d_in[8];
    const float* bfc = (const float*)d_in[9];

    char* wsb = (char*)d_ws;
    size_t o = 0;
    auto alloc = [&](size_t bytes) -> void* {
        void* p = wsb + o;
        o += (bytes + 255) & ~(size_t)255;
        return p;
    };

    f16* xh   = (f16*)alloc((size_t)(NPAD + 1) * 256 * 2); // +1 dummy zero row
    f16* t    = (f16*)alloc((size_t)(NPAD + 1) * 512 * 2); // +1 dummy zero row
    f16* h    = (f16*)alloc((size_t)NPAD * 512 * 2);
    f16* Wt1  = (f16*)alloc(512 * 256 * 2);
    f16* Wt2  = (f16*)alloc(512 * 512 * 2);
    f16* Wt3  = (f16*)alloc(512 * 512 * 2);
    f16* Wtfc = (f16*)alloc(256 * 512 * 2);
    int* deg    = (int*)alloc(N_NODES * 4);
    float* dinv = (float*)alloc(NPAD * 4);                 // f32x4 reads up to NPAD
    int* off    = (int*)alloc((N_NODES + 1) * 4);
    int* cursor = (int*)alloc(N_NODES * 4);
    int* bsum   = (int*)alloc(4096 * 4);
    int* csr    = (int*)alloc(((size_t)E_EDGES + 3 * N_NODES + 8) * 4); // padded

    f16* a1 = t;   // layer-1 agg output [NPAD x 256] aliases t (free until gemm2)

    const int NB = (N_NODES + 255) / 256;   // 391; 391*256 == NPAD exactly

    hipMemsetAsync(deg, 0, N_NODES * 4, stream);
    hipMemsetAsync(cursor, 0, N_NODES * 4, stream);
    hipMemsetAsync(xh + (size_t)NPAD * 256, 0, 256 * 2, stream); // dummy row
    hipMemsetAsync(t  + (size_t)NPAD * 512, 0, 512 * 2, stream); // dummy row

    k_deg<<<(E_EDGES + 255) / 256, 256, 0, stream>>>(ei, deg);
    k_scan1<<<NB, 256, 0, stream>>>(deg, off, bsum, dinv);
    k_scan2<<<1, 512, 0, stream>>>(bsum, NB);
    k_scan3<<<NB, 256, 0, stream>>>(off, bsum, deg, csr);
    k_fill<<<(E_EDGES + 255) / 256, 256, 0, stream>>>(ei, off, cursor, csr);

    k_x_to_f16<<<(N_NODES * 64 + 255) / 256, 256, 0, stream>>>(x, dinv, xh);
    k_transpose<<<dim3(2, 256), 256, 0, stream>>>(W1, Wt1, 256, 512);
    k_transpose<<<dim3(2, 512), 256, 0, stream>>>(W2, Wt2, 512, 512);
    k_transpose<<<dim3(2, 512), 256, 0, stream>>>(W3, Wt3, 512, 512);
    k_transpose<<<dim3(1, 512), 256, 0, stream>>>(Wfc, Wtfc, 512, 256);

    dim3 g4(NPAD / 128, 4), g2(NPAD / 128, 2);
    const int AGG_GRID = N_NODES / 4;   // 25000

    // layer 1: agg(dinv*x) @ W1 (+bias+relu in gemm epilogue)
    k_agg<256, false><<<AGG_GRID, 256, 0, stream>>>(xh, off, csr, dinv, nullptr, a1);
    k_gemm<256, 512, 1><<<g4, 256, 0, stream>>>(a1, Wt1, h, b1, nullptr);
    // layers 2,3: gemm (row-scaled by dinv, contiguous out) then full-width agg
    k_gemm<512, 512, 3><<<g4, 256, 0, stream>>>(h, Wt2, t, nullptr, dinv);
    k_agg<512, true><<<AGG_GRID, 256, 0, stream>>>(t, off, csr, dinv, b2, h);
    k_gemm<512, 512, 3><<<g4, 256, 0, stream>>>(h, Wt3, t, nullptr, dinv);
    k_agg<512, true><<<AGG_GRID, 256, 0, stream>>>(t, off, csr, dinv, b3, h);
    // final FC (fp32 out, guarded)
    k_gemm<512, 256, 2><<<g2, 256, 0, stream>>>(h, Wtfc, d_out, bfc, nullptr);
}

// Round 3
// 883.653 us; speedup vs baseline: 1.0396x; 1.0396x over previous
//
#include <hip/hip_runtime.h>

#define N_NODES 100000
#define NPAD    100096   // 782 * 128; row NPAD is the all-zero dummy row
#define E_EDGES 800000

typedef _Float16 f16;
typedef _Float16 f16x4 __attribute__((ext_vector_type(4)));
typedef _Float16 f16x8 __attribute__((ext_vector_type(8)));
typedef float    f32x4 __attribute__((ext_vector_type(4)));

__device__ inline void async16(const void* g, void* l) {
    __builtin_amdgcn_global_load_lds(
        (const __attribute__((address_space(1))) void*)g,
        (__attribute__((address_space(3))) void*)l, 16, 0, 0);
}

// ---------------- graph build ----------------
__global__ void k_deg(const int* __restrict__ ei, int* __restrict__ deg) {
    int e = blockIdx.x * 256 + threadIdx.x;
    if (e < E_EDGES) atomicAdd(&deg[ei[e]], 1);
}

// scan over PADDED degrees (round up to multiple of 4) so every CSR row is
// a whole number of int4 groups; also emit dinv (zeroed for pad rows).
__global__ void k_scan1(const int* __restrict__ deg, int* __restrict__ off,
                        int* __restrict__ bsum, float* __restrict__ dinv) {
    __shared__ int s[256];
    int i = blockIdx.x * 256 + threadIdx.x;
    int d = (i < N_NODES) ? deg[i] : 0;
    int pd = (d + 3) & ~3;
    // grid covers exactly NPAD indices (391*256); zero dinv for pad rows
    dinv[i] = (i < N_NODES) ? rsqrtf((float)(d + 1)) : 0.f;  // +1 self loop
    s[threadIdx.x] = pd;
    __syncthreads();
    for (int dd = 1; dd < 256; dd <<= 1) {
        int t = (threadIdx.x >= dd) ? s[threadIdx.x - dd] : 0;
        __syncthreads();
        s[threadIdx.x] += t;
        __syncthreads();
    }
    if (i < N_NODES) off[i] = s[threadIdx.x] - pd;   // exclusive
    if (threadIdx.x == 255) bsum[blockIdx.x] = s[255];
}

__global__ void k_scan2(int* __restrict__ bsum, int nb) {
    __shared__ int s[512];
    int tid = threadIdx.x;
    int v = (tid < nb) ? bsum[tid] : 0;
    s[tid] = v;
    __syncthreads();
    for (int d = 1; d < 512; d <<= 1) {
        int t = (tid >= d) ? s[tid - d] : 0;
        __syncthreads();
        s[tid] += t;
        __syncthreads();
    }
    if (tid < nb) bsum[tid] = s[tid] - v;
}

// finalize offsets AND write the (<=3 per node) dummy padding entries
__global__ void k_scan3(int* __restrict__ off, const int* __restrict__ bsum,
                        const int* __restrict__ deg, int* __restrict__ csr) {
    int i = blockIdx.x * 256 + threadIdx.x;
    if (i >= N_NODES) return;
    int o = off[i] + bsum[blockIdx.x];
    off[i] = o;
    int d = deg[i], pd = (d + 3) & ~3;
    for (int k = d; k < pd; ++k) csr[o + k] = NPAD;   // dummy zero row
    if (i == N_NODES - 1) off[N_NODES] = o + pd;
}

__global__ void k_fill(const int* __restrict__ ei, const int* __restrict__ off,
                       int* __restrict__ cursor, int* __restrict__ csr) {
    int e = blockIdx.x * 256 + threadIdx.x;
    if (e >= E_EDGES) return;
    int dst = ei[e];
    int src = ei[E_EDGES + e];
    int pos = atomicAdd(&cursor[dst], 1);
    csr[off[dst] + pos] = src;
}

// ---------------- conversions ----------------
// x -> f16, pre-scaled by dinv[node] (single f16 rounding of the product)
__global__ void k_x_to_f16(const float* __restrict__ x,
                           const float* __restrict__ dinv,
                           f16* __restrict__ xh) {
    int i = blockIdx.x * 256 + threadIdx.x;
    if (i >= N_NODES * 64) return;          // 64 float4 per node (256 ch)
    float d = dinv[i >> 6];
    float4 v = ((const float4*)x)[i];
    f16x4 o;
    o.x = (f16)(v.x * d); o.y = (f16)(v.y * d);
    o.z = (f16)(v.z * d); o.w = (f16)(v.w * d);
    ((f16x4*)xh)[i] = o;
}

__global__ void k_transpose(const float* __restrict__ W, f16* __restrict__ Wt,
                            int K, int M) {
    int m = blockIdx.x * 256 + threadIdx.x;
    int k = blockIdx.y;
    if (m < M) Wt[(size_t)m * K + k] = (f16)W[(size_t)k * M + m];
}

// ---------------- GEMM: C[NPAD x M] = A[NPAD x K] * Bt[M x K]^T ----------------
// 128x128 tile, 4 waves (2x2), wave-tile 64x64, BK=32 (m97 structure).
// 1-D grid, col-tile fast axis, bijective XCD chunk swizzle (m204): the CB
// col-blocks sharing one A-panel run adjacently on the SAME XCD -> A-panel
// is fetched from HBM once and re-served from that XCD's private L2.
// MODE: 0 = raw f16 out, 1 = bias+relu f16 out, 2 = bias f32 out (guarded),
//       3 = row-scale by dsc[row] (dinv pre-scaling), f16 out
template<int K, int M, int MODE>
__launch_bounds__(256, 2)
__global__ void k_gemm(const f16* __restrict__ A, const f16* __restrict__ B,
                       void* __restrict__ C, const float* __restrict__ bias,
                       const float* __restrict__ dsc) {
    __shared__ __align__(16) char smem[16384];
    f16* As = (f16*)smem;             // 128*32 = 8 KB
    f16* Bs = (f16*)(smem + 8192);    // 128*32 = 8 KB
    int tid  = threadIdx.x;
    int wave = tid >> 6, lane = tid & 63;
    int wr = (wave >> 1) * 64, wc = (wave & 1) * 64;
    int lm = lane & 15, q = lane >> 4;

    constexpr int CB  = M / 128;
    constexpr int NWG = (NPAD / 128) * CB;
    constexpr int Q   = NWG / 8, R = NWG % 8;
    int id  = blockIdx.x;
    int xcd = id & 7, pos = id >> 3;
    int nid = (xcd < R) ? xcd * (Q + 1) + pos
                        : R * (Q + 1) + (xcd - R) * Q + pos;
    int rowBase = (nid / CB) * 128;
    int colBase = (nid % CB) * 128;

    f32x4 acc[4][4] = {};
    const f16* Ag = A + (size_t)rowBase * K;
    const f16* Bg = B + (size_t)colBase * K;

    int c0 = tid, c1 = tid + 256;   // 16B chunk ids: row = c>>2, seg = c&3
    for (int kt = 0; kt < K; kt += 32) {
        __syncthreads();
        async16(Ag + (size_t)(c0 >> 2) * K + kt + (c0 & 3) * 8, &As[c0 * 8]);
        async16(Ag + (size_t)(c1 >> 2) * K + kt + (c1 & 3) * 8, &As[c1 * 8]);
        async16(Bg + (size_t)(c0 >> 2) * K + kt + (c0 & 3) * 8, &Bs[c0 * 8]);
        async16(Bg + (size_t)(c1 >> 2) * K + kt + (c1 & 3) * 8, &Bs[c1 * 8]);
        __syncthreads();

        f16x8 a[4], b[4];
#pragma unroll
        for (int i = 0; i < 4; ++i) {
            a[i] = *(const f16x8*)&As[(wr + i * 16 + lm) * 32 + q * 8];
            b[i] = *(const f16x8*)&Bs[(wc + i * 16 + lm) * 32 + q * 8];
        }
#pragma unroll
        for (int i = 0; i < 4; ++i)
#pragma unroll
            for (int j = 0; j < 4; ++j)
                acc[i][j] = __builtin_amdgcn_mfma_f32_16x16x32_f16(
                    a[i], b[j], acc[i][j], 0, 0, 0);
    }

    if (MODE == 2) {
        // fp32 output (final FC) — guarded scalar stores
#pragma unroll
        for (int i = 0; i < 4; ++i) {
            int gr0 = rowBase + wr + i * 16 + q * 4;
#pragma unroll
            for (int j = 0; j < 4; ++j) {
                int gc = colBase + wc + j * 16 + lm;
                float bj = bias[gc];
#pragma unroll
                for (int r = 0; r < 4; ++r) {
                    int gr = gr0 + r;
                    if (gr < N_NODES)
                        ((float*)C)[(size_t)gr * M + gc] = acc[i][j][r] + bj;
                }
            }
        }
    } else {
        // f16 output: LDS transpose -> f16x8 (dwordx4) stores, no guards
        __syncthreads();
        f16* Ep = (f16*)smem + wave * (16 * 80);   // 2560 B/wave, stride 80 f16
#pragma unroll
        for (int i = 0; i < 4; ++i) {
            f32x4 dr = {1.f, 1.f, 1.f, 1.f};
            if (MODE == 3)
                dr = *(const f32x4*)&dsc[rowBase + wr + i * 16 + q * 4];
#pragma unroll
            for (int j = 0; j < 4; ++j) {
                int colg = colBase + wc + j * 16 + lm;
#pragma unroll
                for (int r = 0; r < 4; ++r) {
                    float v = acc[i][j][r];
                    if (MODE == 1) {
                        v += bias[colg];
                        v = v > 0.f ? v : 0.f;
                    }
                    if (MODE == 3) v *= dr[r];
                    Ep[(q * 4 + r) * 80 + j * 16 + lm] = (f16)v;
                }
            }
            __syncthreads();
            int row0 = lane >> 3, c8 = lane & 7;
            f16x8 v0 = *(const f16x8*)&Ep[row0 * 80 + c8 * 8];
            f16x8 v1 = *(const f16x8*)&Ep[(row0 + 8) * 80 + c8 * 8];
            int gr0 = rowBase + wr + i * 16 + row0;
            int gc  = colBase + wc + c8 * 8;
            *(f16x8*)&((f16*)C)[(size_t)gr0 * M + gc] = v0;
            *(f16x8*)&((f16*)C)[(size_t)(gr0 + 8) * M + gc] = v1;
            __syncthreads();
        }
    }
}

// ---------------- aggregation (contiguous, CH channels, prescaled rows) ----------------
// rows of t are already scaled by dinv[src]; CSR rows are padded to x4 with
// the dummy zero row (index NPAD). ONE WAVE PER BLOCK (tail packing), 8
// gathers in flight per main-loop iteration (MLP for the latency-bound case).
template<int VE> struct VecT;
template<> struct VecT<4> { typedef f16x4 type; };
template<> struct VecT<8> { typedef f16x8 type; };

template<int CH, bool ACT>
__launch_bounds__(64)
__global__ void k_agg(const f16* __restrict__ t, const int* __restrict__ off,
                      const int* __restrict__ csr, const float* __restrict__ dinv,
                      const float* __restrict__ bias, f16* __restrict__ h) {
    constexpr int VE = CH / 64;
    typedef typename VecT<VE>::type vec;
    int node = blockIdx.x;
    int lane = threadIdx.x;
    const vec* __restrict__ rows = (const vec*)t;

    vec v = rows[(size_t)node * 64 + lane];   // self (already dinv-scaled)
    float acc[VE];
#pragma unroll
    for (int j = 0; j < VE; ++j) acc[j] = (float)v[j];

    int s = off[node], e = off[node + 1];     // multiple-of-4 row, 16B aligned
    int idx = s;
    for (; idx + 8 <= e; idx += 8) {
        int4 ia = *(const int4*)&csr[idx];
        int4 ib = *(const int4*)&csr[idx + 4];
        vec u0 = rows[(size_t)ia.x * 64 + lane];
        vec u1 = rows[(size_t)ia.y * 64 + lane];
        vec u2 = rows[(size_t)ia.z * 64 + lane];
        vec u3 = rows[(size_t)ia.w * 64 + lane];
        vec u4 = rows[(size_t)ib.x * 64 + lane];
        vec u5 = rows[(size_t)ib.y * 64 + lane];
        vec u6 = rows[(size_t)ib.z * 64 + lane];
        vec u7 = rows[(size_t)ib.w * 64 + lane];
#pragma unroll
        for (int j = 0; j < VE; ++j)
            acc[j] += (((float)u0[j] + (float)u1[j])
                     + ((float)u2[j] + (float)u3[j]))
                    + (((float)u4[j] + (float)u5[j])
                     + ((float)u6[j] + (float)u7[j]));
    }
    if (idx < e) {   // exactly one 4-group left
        int4 ia = *(const int4*)&csr[idx];
        vec u0 = rows[(size_t)ia.x * 64 + lane];
        vec u1 = rows[(size_t)ia.y * 64 + lane];
        vec u2 = rows[(size_t)ia.z * 64 + lane];
        vec u3 = rows[(size_t)ia.w * 64 + lane];
#pragma unroll
        for (int j = 0; j < VE; ++j)
            acc[j] += ((float)u0[j] + (float)u1[j])
                    + ((float)u2[j] + (float)u3[j]);
    }

    float di = dinv[node];
    vec o;
#pragma unroll
    for (int j = 0; j < VE; ++j) {
        float r = di * acc[j];
        if (ACT) {
            r += bias[lane * VE + j];
            r = r > 0.f ? r : 0.f;
        }
        o[j] = (f16)r;
    }
    ((vec*)h)[(size_t)node * 64 + lane] = o;
}

// ---------------- launch ----------------
extern "C" void kernel_launch(void* const* d_in, const int* in_sizes, int n_in,
                              void* d_out, int out_size, void* d_ws, size_t ws_size,
                              hipStream_t stream) {
    const float* x   = (const float*)d_in[0];
    const int*   ei  = (const int*)d_in[1];
    const float* W1  = (const float*)d_in[2];
    const float* b1  = (const float*)d_in[3];
    const float* W2  = (const float*)d_in[4];
    const float* b2  = (const float*)d_in[5];
    const float* W3  = (const float*)d_in[6];
    const float* b3  = (const float*)d_in[7];
    const float* Wfc = (const float*)d_in[8];
    const float* bfc = (const float*)d_in[9];

    char* wsb = (char*)d_ws;
    size_t o = 0;
    auto alloc = [&](size_t bytes) -> void* {
        void* p = wsb + o;
        o += (bytes + 255) & ~(size_t)255;
        return p;
    };

    f16* xh   = (f16*)alloc((size_t)(NPAD + 1) * 256 * 2); // +1 dummy zero row
    f16* t    = (f16*)alloc((size_t)(NPAD + 1) * 512 * 2); // +1 dummy zero row
    f16* h    = (f16*)alloc((size_t)NPAD * 512 * 2);
    f16* Wt1  = (f16*)alloc(512 * 256 * 2);
    f16* Wt2  = (f16*)alloc(512 * 512 * 2);
    f16* Wt3  = (f16*)alloc(512 * 512 * 2);
    f16* Wtfc = (f16*)alloc(256 * 512 * 2);
    int* deg    = (int*)alloc(N_NODES * 4);
    float* dinv = (float*)alloc(NPAD * 4);                 // f32x4 reads up to NPAD
    int* off    = (int*)alloc((N_NODES + 1) * 4);
    int* cursor = (int*)alloc(N_NODES * 4);
    int* bsum   = (int*)alloc(4096 * 4);
    int* csr    = (int*)alloc(((size_t)E_EDGES + 3 * N_NODES + 8) * 4); // padded

    f16* a1 = t;   // layer-1 agg output [NPAD x 256] aliases t (free until gemm2)

    const int NB = (N_NODES + 255) / 256;   // 391; 391*256 == NPAD exactly

    hipMemsetAsync(deg, 0, N_NODES * 4, stream);
    hipMemsetAsync(cursor, 0, N_NODES * 4, stream);
    hipMemsetAsync(xh + (size_t)NPAD * 256, 0, 256 * 2, stream); // dummy row
    hipMemsetAsync(t  + (size_t)NPAD * 512, 0, 512 * 2, stream); // dummy row

    k_deg<<<(E_EDGES + 255) / 256, 256, 0, stream>>>(ei, deg);
    k_scan1<<<NB, 256, 0, stream>>>(deg, off, bsum, dinv);
    k_scan2<<<1, 512, 0, stream>>>(bsum, NB);
    k_scan3<<<NB, 256, 0, stream>>>(off, bsum, deg, csr);
    k_fill<<<(E_EDGES + 255) / 256, 256, 0, stream>>>(ei, off, cursor, csr);

    k_x_to_f16<<<(N_NODES * 64 + 255) / 256, 256, 0, stream>>>(x, dinv, xh);
    k_transpose<<<dim3(2, 256), 256, 0, stream>>>(W1, Wt1, 256, 512);
    k_transpose<<<dim3(2, 512), 256, 0, stream>>>(W2, Wt2, 512, 512);
    k_transpose<<<dim3(2, 512), 256, 0, stream>>>(W3, Wt3, 512, 512);
    k_transpose<<<dim3(1, 512), 256, 0, stream>>>(Wfc, Wtfc, 512, 256);

    constexpr int NWG4 = (NPAD / 128) * 4;   // 3128
    constexpr int NWG2 = (NPAD / 128) * 2;   // 1564

    // layer 1: agg(dinv*x) @ W1 (+bias+relu in gemm epilogue)
    k_agg<256, false><<<N_NODES, 64, 0, stream>>>(xh, off, csr, dinv, nullptr, a1);
    k_gemm<256, 512, 1><<<NWG4, 256, 0, stream>>>(a1, Wt1, h, b1, nullptr);
    // layers 2,3: gemm (row-scaled by dinv, contiguous out) then full-width agg
    k_gemm<512, 512, 3><<<NWG4, 256, 0, stream>>>(h, Wt2, t, nullptr, dinv);
    k_agg<512, true><<<N_NODES, 64, 0, stream>>>(t, off, csr, dinv, b2, h);
    k_gemm<512, 512, 3><<<NWG4, 256, 0, stream>>>(h, Wt3, t, nullptr, dinv);
    k_agg<512, true><<<N_NODES, 64, 0, stream>>>(t, off, csr, dinv, b3, h);
    // final FC (fp32 out, guarded)
    k_gemm<512, 256, 2><<<NWG2, 256, 0, stream>>>(h, Wtfc, d_out, bfc, nullptr);
}